// Round 3
// baseline (268.330 us; speedup 1.0000x reference)
//
#include <hip/hip_runtime.h>
#include <math.h>

#define N_TOTAL 131072
#define BB 8
#define KK 20
#define CC 96
#define LOG2E 1.4426950408889634f

// ---------------- Kernel A: per-block segment (max, sum) partials ----------------
// grid GA blocks x 320 threads; chunk = N/GA contiguous points.
// thread t: k = t%20, sub = t/20 (16 subs); points p = base + sub + 16*i.
// Partials written TRANSPOSED: mPartT[cell*GA + block] so kernel B reads coalesced.
#define GA 512
#define CHUNKA (N_TOTAL / GA)   // 256
#define SUBS 16
#define THRA 320

__global__ __launch_bounds__(THRA) void seg_ms_kernel(
    const float* __restrict__ probs, const int* __restrict__ bidx,
    float* __restrict__ mPartT, float* __restrict__ sPartT) {
  __shared__ float lm[SUBS][BB][KK];
  __shared__ float ls[SUBS][BB][KK];
  const int t = threadIdx.x;
  const int k = t % KK, sub = t / KK;
  for (int i = t; i < SUBS * BB * KK; i += THRA) {
    ((float*)lm)[i] = -1e30f;
    ((float*)ls)[i] = 0.f;
  }
  __syncthreads();
  const int base = blockIdx.x * CHUNKA;
  float m = -1e30f, s = 0.f;
  int cb = bidx[base + sub];
  #pragma unroll 4
  for (int i = 0; i < CHUNKA / SUBS; ++i) {
    const int p = base + sub + i * SUBS;
    const float q = probs[(size_t)p * KK + k] * LOG2E;
    const int b = bidx[p];
    if (b != cb) {           // sorted -> each b visited at most once per thread
      lm[sub][cb][k] = m; ls[sub][cb][k] = s;
      m = -1e30f; s = 0.f; cb = b;
    }
    const float mn = fmaxf(m, q);
    s = s * exp2f(m - mn) + exp2f(q - mn);
    m = mn;
  }
  lm[sub][cb][k] = m; ls[sub][cb][k] = s;
  __syncthreads();
  if (t < BB * KK) {
    const int b = t / KK, kk = t % KK;
    float M = -1e30f, S = 0.f;
    #pragma unroll
    for (int u = 0; u < SUBS; ++u) {
      const float m2 = lm[u][b][kk], s2 = ls[u][b][kk];
      const float Mn = fmaxf(M, m2);
      S = S * exp2f(M - Mn) + s2 * exp2f(m2 - Mn);
      M = Mn;
    }
    mPartT[(size_t)t * GA + blockIdx.x] = M;
    sPartT[(size_t)t * GA + blockIdx.x] = S;
  }
}

// ---------------- Kernel B: reduce partials -> off[cell] = M + log2(S) ----------------
// 40 blocks x 256 threads; 4 cells/block, 64 lanes/cell, coalesced reads + shfl reduce.
__global__ __launch_bounds__(256) void seg_off_kernel(
    const float* __restrict__ mPartT, const float* __restrict__ sPartT,
    float* __restrict__ off) {
  const int lane = threadIdx.x & 63;
  const int cl = threadIdx.x >> 6;
  const int cell = blockIdx.x * 4 + cl;
  const float* mp = mPartT + (size_t)cell * GA;
  const float* sp = sPartT + (size_t)cell * GA;
  float M = -1e30f;
  #pragma unroll
  for (int i = 0; i < GA / 64; ++i)
    M = fmaxf(M, mp[lane + i * 64]);
  #pragma unroll
  for (int d = 1; d < 64; d <<= 1)
    M = fmaxf(M, __shfl_xor(M, d));
  float S = 0.f;
  #pragma unroll
  for (int i = 0; i < GA / 64; ++i)
    S += sp[lane + i * 64] * exp2f(mp[lane + i * 64] - M);
  #pragma unroll
  for (int d = 1; d < 64; d <<= 1)
    S += __shfl_xor(S, d);
  if (lane == 0)
    off[cell] = (S > 0.f) ? (M + log2f(S)) : 3e38f;
}

// ---------------- Kernel C: weighted aggregation ----------------
// grid GC x 1024; chunk = 256 contiguous points per block.
// active threads 960: pslot = t/60 (16 point-slots), r = t%60,
// kg = r/12 (4 k's), cg = r%12 (8 c's). acc[4][8] in registers, 16 passes.
// All __syncthreads() at top level (uniform).
#define GC 512
#define CHUNKC (N_TOTAL / GC)   // 256
#define PSL 16
#define TPP 60
#define ACTIVE (PSL * TPP)      // 960
#define THRC 1024

__global__ __launch_bounds__(THRC, 8) void gather_kernel(
    const float* __restrict__ feats, const float* __restrict__ probs,
    const int* __restrict__ bidx, const float* __restrict__ off,
    float* __restrict__ out) {
  __shared__ float loff[BB * KK];
  __shared__ float lacc[32 * TPP];   // layout [v][r]: addr v*60+r (banks spread by r)
  const int t = threadIdx.x;
  if (t < BB * KK) loff[t] = off[t];
  for (int i = t; i < 32 * TPP; i += THRC) lacc[i] = 0.f;
  __syncthreads();

  const bool active = t < ACTIVE;
  const int pslot = t / TPP, r = t % TPP;
  const int kg = r / 12, cg = r % 12;
  const int base = blockIdx.x * CHUNKC;
  const int b0 = bidx[base];
  const bool multi = b0 != bidx[base + CHUNKC - 1];  // block-uniform

  float acc[4][8];
  #pragma unroll
  for (int i = 0; i < 4; ++i)
    #pragma unroll
    for (int j = 0; j < 8; ++j) acc[i][j] = 0.f;
  int cb = b0;

  if (active) {
    int n = base + pslot;
    cb = bidx[n];
    float offr[4];
    #pragma unroll
    for (int i = 0; i < 4; ++i) offr[i] = loff[cb * KK + kg * 4 + i];

    const float* pp = probs + (size_t)n * KK + kg * 4;
    const float* fp = feats + (size_t)n * CC + cg * 8;
    float4 pv = *(const float4*)pp;
    float4 f0 = *(const float4*)fp;
    float4 f1 = *(const float4*)(fp + 4);
    int b = cb;

    const int PASSES = CHUNKC / PSL;  // 16
    for (int pass = 0; pass < PASSES; ++pass) {
      const int adv = (pass + 1 < PASSES) ? PSL : 0;
      const float* pp2 = pp + (size_t)adv * KK;
      const float* fp2 = fp + (size_t)adv * CC;
      // 1-deep pipeline: issue next loads before computing current
      const float4 pvn = *(const float4*)pp2;
      const float4 f0n = *(const float4*)fp2;
      const float4 f1n = *(const float4*)(fp2 + 4);
      const int bn = bidx[n + adv];

      if (multi && b != cb) {   // rare slow path (batch boundary inside chunk)
        #pragma unroll
        for (int i = 0; i < 4; ++i)
          #pragma unroll
          for (int j = 0; j < 8; ++j) {
            atomicAdd(out + cb * (KK * CC) + (kg * 4 + i) * CC + cg * 8 + j, acc[i][j]);
            acc[i][j] = 0.f;
          }
        cb = b;
        #pragma unroll
        for (int i = 0; i < 4; ++i) offr[i] = loff[cb * KK + kg * 4 + i];
      }

      float wr[4];
      wr[0] = exp2f(fmaf(pv.x, LOG2E, -offr[0]));
      wr[1] = exp2f(fmaf(pv.y, LOG2E, -offr[1]));
      wr[2] = exp2f(fmaf(pv.z, LOG2E, -offr[2]));
      wr[3] = exp2f(fmaf(pv.w, LOG2E, -offr[3]));
      const float fr[8] = {f0.x, f0.y, f0.z, f0.w, f1.x, f1.y, f1.z, f1.w};
      #pragma unroll
      for (int i = 0; i < 4; ++i)
        #pragma unroll
        for (int j = 0; j < 8; ++j)
          acc[i][j] = fmaf(wr[i], fr[j], acc[i][j]);

      pv = pvn; f0 = f0n; f1 = f1n; b = bn;
      pp = pp2; fp = fp2; n += adv;
    }
  }

  // ---- flush (uniform barrier structure) ----
  if (active) {
    if (multi) {
      #pragma unroll
      for (int i = 0; i < 4; ++i)
        #pragma unroll
        for (int j = 0; j < 8; ++j)
          atomicAdd(out + cb * (KK * CC) + (kg * 4 + i) * CC + cg * 8 + j, acc[i][j]);
    } else {
      // cross-pslot reduce in LDS: addr (i*8+j)*60 + r -> banks spread by r
      #pragma unroll
      for (int i = 0; i < 4; ++i)
        #pragma unroll
        for (int j = 0; j < 8; ++j)
          atomicAdd(&lacc[(i * 8 + j) * TPP + r], acc[i][j]);
    }
  }
  __syncthreads();
  if (!multi) {
    for (int c = t; c < 32 * TPP; c += THRC) {
      const int v = c / TPP, rr = c % TPP;
      const int kg2 = rr / 12, cg2 = rr % 12;
      const int ii = v / 8, jj = v % 8;
      atomicAdd(out + b0 * (KK * CC) + (kg2 * 4 + ii) * CC + cg2 * 8 + jj, lacc[c]);
    }
  }
}

extern "C" void kernel_launch(void* const* d_in, const int* in_sizes, int n_in,
                              void* d_out, int out_size, void* d_ws, size_t ws_size,
                              hipStream_t stream) {
  const float* feats = (const float*)d_in[0];
  const float* probs = (const float*)d_in[1];
  const int* bidx = (const int*)d_in[3];
  float* out = (float*)d_out;

  float* mPartT = (float*)d_ws;                  // [160][GA]
  float* sPartT = mPartT + (size_t)GA * BB * KK; // [160][GA]
  float* off    = sPartT + (size_t)GA * BB * KK; // [160]

  hipMemsetAsync(d_out, 0, (size_t)BB * KK * CC * sizeof(float), stream);
  seg_ms_kernel<<<GA, THRA, 0, stream>>>(probs, bidx, mPartT, sPartT);
  seg_off_kernel<<<BB * KK / 4, 256, 0, stream>>>(mPartT, sPartT, off);
  gather_kernel<<<GC, THRC, 0, stream>>>(feats, probs, bidx, off, out);
}

// Round 4
// 149.619 us; speedup vs baseline: 1.7934x; 1.7934x over previous
//
#include <hip/hip_runtime.h>
#include <math.h>

#define N_TOTAL 131072
#define BB 8
#define KK 20
#define CC 96
#define LOG2E 1.4426950408889634f

// ============ Kernel A: per-block segment (max,sum) partials ============
// 512 blocks x 320 threads, 256-point chunk staged in LDS.
// Partials transposed: mPartT[cell*GA + block] for coalesced kernel-B reads.
#define GA 512
#define CHUNKA 256
#define THRA 320
#define SUBS 16

__global__ __launch_bounds__(THRA) void seg_ms_kernel(
    const float* __restrict__ probs, const int* __restrict__ bidx,
    float* __restrict__ mPartT, float* __restrict__ sPartT) {
  __shared__ float plds[CHUNKA * KK];     // 20 KB
  __shared__ float lm[SUBS][BB][KK];      // 10 KB
  __shared__ float ls[SUBS][BB][KK];      // 10 KB
  const int t = threadIdx.x;
  const int base = blockIdx.x * CHUNKA;
  // stage probs chunk, coalesced float4 (1280 float4 / 320 thr = 4 each)
  const float4* src = (const float4*)(probs + (size_t)base * KK);
  float4* dst = (float4*)plds;
  #pragma unroll
  for (int i = 0; i < 4; ++i) dst[t + i * THRA] = src[t + i * THRA];
  for (int i = t; i < SUBS * BB * KK; i += THRA) {
    ((float*)lm)[i] = -1e30f; ((float*)ls)[i] = 0.f;
  }
  const int b0 = bidx[base];
  const bool multi = b0 != bidx[base + CHUNKA - 1];
  __syncthreads();
  const int k = t % KK, sub = t / KK;
  if (!multi) {
    // fast path: two-pass, independent exp2 (no serial chain)
    float M = -1e30f;
    #pragma unroll
    for (int i = 0; i < CHUNKA / SUBS; ++i)
      M = fmaxf(M, plds[(sub + i * SUBS) * KK + k]);
    M *= LOG2E;
    float S = 0.f;
    #pragma unroll
    for (int i = 0; i < CHUNKA / SUBS; ++i)
      S += exp2f(fmaf(plds[(sub + i * SUBS) * KK + k], LOG2E, -M));
    lm[sub][b0][k] = M; ls[sub][b0][k] = S;
  } else {
    // rare boundary path: online with flush (sorted -> each b once per thread)
    float m = -1e30f, s = 0.f;
    int cb = bidx[base + sub];
    for (int i = 0; i < CHUNKA / SUBS; ++i) {
      const int p = sub + i * SUBS;
      const float q = plds[p * KK + k] * LOG2E;
      const int b = bidx[base + p];
      if (b != cb) { lm[sub][cb][k] = m; ls[sub][cb][k] = s;
                     m = -1e30f; s = 0.f; cb = b; }
      const float mn = fmaxf(m, q);
      s = s * exp2f(m - mn) + exp2f(q - mn);
      m = mn;
    }
    lm[sub][cb][k] = m; ls[sub][cb][k] = s;
  }
  __syncthreads();
  if (t < BB * KK) {
    const int b = t / KK, kk2 = t % KK;
    float M = -1e30f, S = 0.f;
    #pragma unroll
    for (int u = 0; u < SUBS; ++u) {
      const float m2 = lm[u][b][kk2], s2 = ls[u][b][kk2];
      const float Mn = fmaxf(M, m2);
      S = S * exp2f(M - Mn) + s2 * exp2f(m2 - Mn);
      M = Mn;
    }
    mPartT[(size_t)t * GA + blockIdx.x] = M;
    sPartT[(size_t)t * GA + blockIdx.x] = S;
  }
}

// ============ Kernel B: reduce partials -> off[cell] = M + log2(S) ============
// 40 blocks x 256 threads; 4 cells/block, 64 lanes/cell, coalesced + shfl.
__global__ __launch_bounds__(256) void seg_off_kernel(
    const float* __restrict__ mPartT, const float* __restrict__ sPartT,
    float* __restrict__ off) {
  const int lane = threadIdx.x & 63;
  const int cl = threadIdx.x >> 6;
  const int cell = blockIdx.x * 4 + cl;
  const float* mp = mPartT + (size_t)cell * GA;
  const float* sp = sPartT + (size_t)cell * GA;
  float M = -1e30f;
  #pragma unroll
  for (int i = 0; i < GA / 64; ++i) M = fmaxf(M, mp[lane + i * 64]);
  #pragma unroll
  for (int d = 1; d < 64; d <<= 1) M = fmaxf(M, __shfl_xor(M, d));
  float S = 0.f;
  #pragma unroll
  for (int i = 0; i < GA / 64; ++i)
    S += sp[lane + i * 64] * exp2f(mp[lane + i * 64] - M);
  #pragma unroll
  for (int d = 1; d < 64; d <<= 1) S += __shfl_xor(S, d);
  if (lane == 0) off[cell] = (S > 0.f) ? (M + log2f(S)) : 3e38f;
}

// ============ Kernel C: weighted aggregation ============
// 512 blocks x 512 threads, one 256-point chunk per block.
// Phase W: coalesced probs load -> w = exp2(fma(p,log2e,-off)) ONCE into LDS.
// Phase F: 480 active threads: pslot=t/60 (8 slots), r=t%60, kg=r/12 (4 k),
//          cg=r%12 (8 c). acc[4][8]; w via ds_read_b128; feats 2-deep prefetch.
// All barriers top-level/uniform.
#define GC 512
#define CHUNKC 256
#define THRC 512
#define PSLOTS 8
#define TPP 60
#define ACTIVE (PSLOTS * TPP)   // 480
#define PASSES (CHUNKC / PSLOTS) // 32

__global__ __launch_bounds__(THRC, 4) void gather_kernel(
    const float* __restrict__ feats, const float* __restrict__ probs,
    const int* __restrict__ bidx, const float* __restrict__ off,
    float* __restrict__ out) {
  __shared__ float loff[BB * KK];       // 640 B
  __shared__ float wlds[CHUNKC * KK];   // 20 KB
  __shared__ float lacc[KK * CC];       // 7.5 KB
  const int t = threadIdx.x;
  const int base = blockIdx.x * CHUNKC;
  const int b0 = bidx[base];
  const bool multi = b0 != bidx[base + CHUNKC - 1];

  if (t < BB * KK) loff[t] = off[t];
  for (int i = t; i < KK * CC; i += THRC) lacc[i] = 0.f;

  // ---- issue probs loads (coalesced; 1280 float4, 2-3 per thread) ----
  const float4* psrc = (const float4*)(probs + (size_t)base * KK);
  const float4 pv0 = psrc[t];
  const float4 pv1 = psrc[t + THRC];
  float4 pv2;
  if (t < 256) pv2 = psrc[t + 2 * THRC];

  // ---- issue first feats prefetch (overlaps w-phase) ----
  const bool active = t < ACTIVE;
  const int pslot = t / TPP, r = t % TPP;
  const int kg = r / 12, cg = r % 12;
  const float* fbase = feats + (size_t)(base + pslot) * CC + cg * 8;
  float4 fa0, fa1, fb0, fb1;
  if (active) {
    fa0 = *(const float4*)(fbase);
    fa1 = *(const float4*)(fbase + 4);
    fb0 = *(const float4*)(fbase + PSLOTS * CC);
    fb1 = *(const float4*)(fbase + PSLOTS * CC + 4);
  }

  __syncthreads();   // loff ready

  // ---- w-phase: compute weights once, store to LDS ----
  {
    float4* wdst = (float4*)wlds;
    // element group i4: point n = i4/5, k0 = (i4%5)*4
    {
      const int i4 = t; const int n = i4 / 5, k0 = (i4 % 5) * 4;
      const int b = multi ? bidx[base + n] : b0;
      const float* lo = &loff[b * KK + k0];
      float4 w;
      w.x = exp2f(fmaf(pv0.x, LOG2E, -lo[0]));
      w.y = exp2f(fmaf(pv0.y, LOG2E, -lo[1]));
      w.z = exp2f(fmaf(pv0.z, LOG2E, -lo[2]));
      w.w = exp2f(fmaf(pv0.w, LOG2E, -lo[3]));
      wdst[i4] = w;
    }
    {
      const int i4 = t + THRC; const int n = i4 / 5, k0 = (i4 % 5) * 4;
      const int b = multi ? bidx[base + n] : b0;
      const float* lo = &loff[b * KK + k0];
      float4 w;
      w.x = exp2f(fmaf(pv1.x, LOG2E, -lo[0]));
      w.y = exp2f(fmaf(pv1.y, LOG2E, -lo[1]));
      w.z = exp2f(fmaf(pv1.z, LOG2E, -lo[2]));
      w.w = exp2f(fmaf(pv1.w, LOG2E, -lo[3]));
      wdst[i4] = w;
    }
    if (t < 256) {
      const int i4 = t + 2 * THRC; const int n = i4 / 5, k0 = (i4 % 5) * 4;
      const int b = multi ? bidx[base + n] : b0;
      const float* lo = &loff[b * KK + k0];
      float4 w;
      w.x = exp2f(fmaf(pv2.x, LOG2E, -lo[0]));
      w.y = exp2f(fmaf(pv2.y, LOG2E, -lo[1]));
      w.z = exp2f(fmaf(pv2.z, LOG2E, -lo[2]));
      w.w = exp2f(fmaf(pv2.w, LOG2E, -lo[3]));
      wdst[i4] = w;
    }
  }
  __syncthreads();   // wlds ready (also covers lacc init)

  // ---- FMA phase ----
  float acc[4][8];
  #pragma unroll
  for (int i = 0; i < 4; ++i)
    #pragma unroll
    for (int j = 0; j < 8; ++j) acc[i][j] = 0.f;

  if (active) {
    const float* wp = wlds + pslot * KK + kg * 4;  // +pass*8*KK per pass; 16B-aligned
    if (!multi) {
      for (int pass = 0; pass < PASSES; pass += 2) {
        const int np0 = (pass + 2 < PASSES) ? pass + 2 : pass;
        const int np1 = (pass + 3 < PASSES) ? pass + 3 : pass + 1;
        const float4 fc0 = *(const float4*)(fbase + (size_t)np0 * PSLOTS * CC);
        const float4 fc1 = *(const float4*)(fbase + (size_t)np0 * PSLOTS * CC + 4);
        const float4 fd0 = *(const float4*)(fbase + (size_t)np1 * PSLOTS * CC);
        const float4 fd1 = *(const float4*)(fbase + (size_t)np1 * PSLOTS * CC + 4);

        float4 w = *(const float4*)(wp + (size_t)pass * PSLOTS * KK);
        {
          const float fr[8] = {fa0.x, fa0.y, fa0.z, fa0.w, fa1.x, fa1.y, fa1.z, fa1.w};
          const float wr[4] = {w.x, w.y, w.z, w.w};
          #pragma unroll
          for (int i = 0; i < 4; ++i)
            #pragma unroll
            for (int j = 0; j < 8; ++j) acc[i][j] = fmaf(wr[i], fr[j], acc[i][j]);
        }
        float4 w2 = *(const float4*)(wp + (size_t)(pass + 1) * PSLOTS * KK);
        {
          const float fr[8] = {fb0.x, fb0.y, fb0.z, fb0.w, fb1.x, fb1.y, fb1.z, fb1.w};
          const float wr[4] = {w2.x, w2.y, w2.z, w2.w};
          #pragma unroll
          for (int i = 0; i < 4; ++i)
            #pragma unroll
            for (int j = 0; j < 8; ++j) acc[i][j] = fmaf(wr[i], fr[j], acc[i][j]);
        }
        fa0 = fc0; fa1 = fc1; fb0 = fd0; fb1 = fd1;
      }
    } else {
      // rare boundary block: per-pass bidx tracking + atomic flush at boundary
      int cb = bidx[base + pslot];
      for (int pass = 0; pass < PASSES; ++pass) {
        const int n = pass * PSLOTS + pslot;
        const int b = bidx[base + n];
        if (b != cb) {
          #pragma unroll
          for (int i = 0; i < 4; ++i)
            #pragma unroll
            for (int j = 0; j < 8; ++j) {
              atomicAdd(out + cb * (KK * CC) + (kg * 4 + i) * CC + cg * 8 + j, acc[i][j]);
              acc[i][j] = 0.f;
            }
          cb = b;
        }
        const float4 w = *(const float4*)(wp + (size_t)pass * PSLOTS * KK);
        const float4 g0 = *(const float4*)(fbase + (size_t)pass * PSLOTS * CC);
        const float4 g1 = *(const float4*)(fbase + (size_t)pass * PSLOTS * CC + 4);
        const float fr[8] = {g0.x, g0.y, g0.z, g0.w, g1.x, g1.y, g1.z, g1.w};
        const float wr[4] = {w.x, w.y, w.z, w.w};
        #pragma unroll
        for (int i = 0; i < 4; ++i)
          #pragma unroll
          for (int j = 0; j < 8; ++j) acc[i][j] = fmaf(wr[i], fr[j], acc[i][j]);
      }
      // final flush for multi blocks
      #pragma unroll
      for (int i = 0; i < 4; ++i)
        #pragma unroll
        for (int j = 0; j < 8; ++j)
          atomicAdd(out + cb * (KK * CC) + (kg * 4 + i) * CC + cg * 8 + j, acc[i][j]);
    }
  }

  // ---- flush: LDS reduce across pslots, then 1920 global atomics ----
  if (active && !multi) {
    #pragma unroll
    for (int i = 0; i < 4; ++i)
      #pragma unroll
      for (int j = 0; j < 8; ++j)
        atomicAdd(&lacc[(kg * 4 + i) * CC + cg * 8 + j], acc[i][j]);
  }
  __syncthreads();
  if (!multi) {
    for (int i = t; i < KK * CC; i += THRC)
      atomicAdd(out + (size_t)b0 * (KK * CC) + i, lacc[i]);
  }
}

extern "C" void kernel_launch(void* const* d_in, const int* in_sizes, int n_in,
                              void* d_out, int out_size, void* d_ws, size_t ws_size,
                              hipStream_t stream) {
  const float* feats = (const float*)d_in[0];
  const float* probs = (const float*)d_in[1];
  const int* bidx = (const int*)d_in[3];
  float* out = (float*)d_out;

  float* mPartT = (float*)d_ws;                  // [160][GA]
  float* sPartT = mPartT + (size_t)GA * BB * KK; // [160][GA]
  float* off    = sPartT + (size_t)GA * BB * KK; // [160]

  hipMemsetAsync(d_out, 0, (size_t)BB * KK * CC * sizeof(float), stream);
  seg_ms_kernel<<<GA, THRA, 0, stream>>>(probs, bidx, mPartT, sPartT);
  seg_off_kernel<<<BB * KK / 4, 256, 0, stream>>>(mPartT, sPartT, off);
  gather_kernel<<<GC, THRC, 0, stream>>>(feats, probs, bidx, off, out);
}